// Round 25
// baseline (83.319 us; speedup 1.0000x reference)
//
#include <hip/hip_runtime.h>

#define BATCH 4096
#define SEQ   80
#define EMBED 100
#define UNITS 64
#define NTILE (BATCH / 16)      // 256 tiles, one wave each
#define NVOC  10000
#define NVWV  ((NVOC + 15) / 16)
#define CHK   20                // steps per chunk
#define NCHK  (SEQ / CHK)       // 4 chunks

typedef float f32x4  __attribute__((ext_vector_type(4)));
typedef short bf16x8 __attribute__((ext_vector_type(8)));

#define MFMA16 __builtin_amdgcn_mfma_f32_16x16x32_bf16

// ---- ws layout (bytes) ----
#define TAB_OFF 0u           // uint2 table2[10000][16] = 1,280,000 B (L2-resident)

__device__ __forceinline__ unsigned f2bfu(float f) {
    union { float f; unsigned u; } x; x.f = f;
    return (x.u + 0x7fffu + ((x.u >> 16) & 1u)) >> 16;   // RNE
}
__device__ __forceinline__ unsigned cvtpk(float lo, float hi) {
    unsigned r;
    asm("v_cvt_pk_bf16_f32 %0, %1, %2" : "=v"(r) : "v"(lo), "v"(hi));
    return r;
}
__device__ __forceinline__ float bflo(unsigned u) {
    union { unsigned u; float f; } x; x.u = u << 16; return x.f;
}
__device__ __forceinline__ float bfhi(unsigned u) {
    union { unsigned u; float f; } x; x.u = u & 0xffff0000u; return x.f;
}
// branch-free exact-tails tanh: 1 - 2/(e^{2x}+1)
__device__ __forceinline__ float fast_tanh(float x) {
    float e = __builtin_amdgcn_exp2f(x * 2.8853900817779268f);
    float r = __builtin_amdgcn_rcpf(e + 1.0f);
    return __builtin_fmaf(-2.0f, r, 1.0f);
}
// permuted unit assignment (R2/R3-verified): D slot (mt,reg) == B slot in-lane
__device__ __forceinline__ int uperm(int mt, int m15) {
    return 8 * (m15 >> 2) + 4 * (mt & 1) + (m15 & 3) + 32 * (mt >> 1);
}

// ---------------------------------------------------------------------------
// tableproj: table2[v] = b1 + emb[v] @ W1 in UPERM-packed order:
// slot [v][kgrp*4+mt] = uint2{pk(acc[mt][0..1]), pk(acc[mt][2..3])}.
// Same per-unit arithmetic/rounding as R24 (A rows relabeled via uperm).
// ---------------------------------------------------------------------------
__global__ __launch_bounds__(256) void tableproj_kernel(
    const float* __restrict__ emb,
    const float* __restrict__ b1,
    const float* __restrict__ W1,
    uint2* __restrict__ table2)
{
    const int lane = threadIdx.x & 63;
    const int wid  = threadIdx.x >> 6;
    const int gw   = blockIdx.x * 4 + wid;
    if (gw >= NVWV) return;
    const int m15  = lane & 15;
    const int kgrp = lane >> 4;
    const int v    = gw * 16 + m15;
    const int vc   = v < NVOC ? v : NVOC - 1;

    bf16x8 aW1[4][4];
    #pragma unroll
    for (int mt = 0; mt < 4; ++mt) {
        const int u = uperm(mt, m15);
        #pragma unroll
        for (int ks = 0; ks < 4; ++ks)
            #pragma unroll
            for (int j = 0; j < 8; ++j) {
                const int k = kgrp * 8 + j + 32 * ks;
                aW1[mt][ks][j] = (k < EMBED) ? (short)f2bfu(W1[k * UNITS + u])
                                             : (short)0;
            }
    }

    const float* rp = emb + (size_t)vc * EMBED;
    bf16x8 bf[4];
    #pragma unroll
    for (int ks = 0; ks < 3; ++ks) {
        f32x4 e0 = *(const f32x4*)(rp + kgrp * 8 + 32 * ks);
        f32x4 e1 = *(const f32x4*)(rp + kgrp * 8 + 32 * ks + 4);
        uint4 u;
        u.x = cvtpk(e0.x, e0.y); u.y = cvtpk(e0.z, e0.w);
        u.z = cvtpk(e1.x, e1.y); u.w = cvtpk(e1.z, e1.w);
        bf[ks] = *(bf16x8*)&u;
    }
    {
        uint4 u = {0u, 0u, 0u, 0u};
        if (kgrp == 0) {
            f32x4 e0 = *(const f32x4*)(rp + 96);
            u.x = cvtpk(e0.x, e0.y); u.y = cvtpk(e0.z, e0.w);
        }
        bf[3] = *(bf16x8*)&u;
    }

    f32x4 acc[4];
    #pragma unroll
    for (int mt = 0; mt < 4; ++mt)
        acc[mt] = *(const f32x4*)(b1 + 8 * kgrp + 4 * (mt & 1) + 32 * (mt >> 1));
    #pragma unroll
    for (int ks = 0; ks < 4; ++ks)
        #pragma unroll
        for (int mt = 0; mt < 4; ++mt)
            acc[mt] = MFMA16(aW1[mt][ks], bf[ks], acc[mt], 0, 0, 0);

    #pragma unroll
    for (int mt = 0; mt < 4; ++mt) {
        uint2 q;
        q.x = cvtpk(acc[mt][0], acc[mt][1]);
        q.y = cvtpk(acc[mt][2], acc[mt][3]);
        table2[(size_t)v * 16 + kgrp * 4 + mt] = q;
    }
}

// ---------------------------------------------------------------------------
// rnn: two-pass register-resident scan. One wave per 16-row tile, NO
// barriers, NO cross-wave exchange. Per 20-step chunk: pass A runs the h1
// chain (xw C-init + U1, 8 MFMA + 16 tanh/step) writing packed h1 B-frags
// to LDS (in-wave); pass B runs the h2 chain (W2·h1 from LDS + U2,
// 16 MFMA + 16 tanh/step). uperm D->B handoff (R3-verified) keeps both
// recurrences fully in registers.
// ---------------------------------------------------------------------------
__global__ __launch_bounds__(64, 1) void rnn_kernel(
    const int*    __restrict__ tokens,
    const uint2*  __restrict__ table2,   // [10000][16] uint2, uperm-packed
    const float*  __restrict__ U1,
    const float*  __restrict__ W2,
    const float*  __restrict__ U2,
    const float*  __restrict__ b2,
    const float*  __restrict__ Wo,
    const float*  __restrict__ bo,
    float*        __restrict__ out)
{
    __shared__ __align__(16) uint4 h1S[CHK][64][2];   // 40,960 B

    const int lane = threadIdx.x;
    const int wg   = blockIdx.x;
    const int m15  = lane & 15;
    const int kgrp = lane >> 4;
    const int* tokp = tokens + (size_t)(wg * 16 + m15) * SEQ;

    // uperm weight A-frags (same values/rounding as always: f2bfu of f32)
    bf16x8 aU1[4][2], aW2[4][2], aU2[4][2];
    #pragma unroll
    for (int mt = 0; mt < 4; ++mt) {
        const int u = uperm(mt, m15);
        #pragma unroll
        for (int ks = 0; ks < 2; ++ks)
            #pragma unroll
            for (int j = 0; j < 8; ++j) {
                const int k = kgrp * 8 + j + 32 * ks;
                aU1[mt][ks][j] = (short)f2bfu(U1[k * UNITS + u]);
                aW2[mt][ks][j] = (short)f2bfu(W2[k * UNITS + u]);
                aU2[mt][ks][j] = (short)f2bfu(U2[k * UNITS + u]);
            }
    }
    f32x4 b2c[4];
    #pragma unroll
    for (int mt = 0; mt < 4; ++mt)
        b2c[mt] = *(const f32x4*)(b2 + 8 * kgrp + 4 * (mt & 1) + 32 * (mt >> 1));

    uint4 pb1[2], pb2[2];
    pb1[0] = pb1[1] = pb2[0] = pb2[1] = uint4{0u, 0u, 0u, 0u};
    f32x4 d2[4];

    for (int c = 0; c < NCHK; ++c) {
        const int tbase = c * CHK;

        // ================= pass A: h1 chain, 20 steps =================
        uint4 q0, q1;
        {
            const uint4* qp = (const uint4*)(table2 +
                              (size_t)tokp[tbase] * 16 + kgrp * 4);
            q0 = qp[0]; q1 = qp[1];
        }
        int tokC = tokp[(tbase + 1 < SEQ) ? tbase + 1 : SEQ - 1];

        for (int i = 0; i < CHK; ++i) {
            // prefetch next step's feed (independent of the chain)
            const uint4* qn = (const uint4*)(table2 +
                              (size_t)tokC * 16 + kgrp * 4);
            uint4 n0 = qn[0], n1 = qn[1];
            {
                int tn = tbase + i + 2;
                tokC = tokp[(tn < SEQ) ? tn : SEQ - 1];
            }

            f32x4 d1[4];
            d1[0] = {bflo(q0.x), bfhi(q0.x), bflo(q0.y), bfhi(q0.y)};
            d1[1] = {bflo(q0.z), bfhi(q0.z), bflo(q0.w), bfhi(q0.w)};
            d1[2] = {bflo(q1.x), bfhi(q1.x), bflo(q1.y), bfhi(q1.y)};
            d1[3] = {bflo(q1.z), bfhi(q1.z), bflo(q1.w), bfhi(q1.w)};
            #pragma unroll
            for (int mt = 0; mt < 4; ++mt) {
                d1[mt] = MFMA16(aU1[mt][0], *(const bf16x8*)&pb1[0], d1[mt], 0, 0, 0);
                d1[mt] = MFMA16(aU1[mt][1], *(const bf16x8*)&pb1[1], d1[mt], 0, 0, 0);
            }
            #pragma unroll
            for (int mt = 0; mt < 4; ++mt)
                #pragma unroll
                for (int r = 0; r < 4; ++r) d1[mt][r] = fast_tanh(d1[mt][r]);
            #pragma unroll
            for (int ks = 0; ks < 2; ++ks) {
                pb1[ks].x = cvtpk(d1[2 * ks][0],     d1[2 * ks][1]);
                pb1[ks].y = cvtpk(d1[2 * ks][2],     d1[2 * ks][3]);
                pb1[ks].z = cvtpk(d1[2 * ks + 1][0], d1[2 * ks + 1][1]);
                pb1[ks].w = cvtpk(d1[2 * ks + 1][2], d1[2 * ks + 1][3]);
            }
            h1S[i][lane][0] = pb1[0];
            h1S[i][lane][1] = pb1[1];
            q0 = n0; q1 = n1;
        }

        // ================= pass B: h2 chain, 20 steps =================
        // (same wave wrote h1S; program order + compiler lgkmcnt = no barrier)
        for (int i = 0; i < CHK; ++i) {
            uint4 p0 = h1S[i][lane][0];
            uint4 p1 = h1S[i][lane][1];
            f32x4 dC[4], dD[4];
            #pragma unroll
            for (int mt = 0; mt < 4; ++mt) {
                f32x4 a = b2c[mt];
                a = MFMA16(aW2[mt][0], *(const bf16x8*)&p0, a, 0, 0, 0);
                a = MFMA16(aW2[mt][1], *(const bf16x8*)&p1, a, 0, 0, 0);
                dC[mt] = a;
                f32x4 z = {0.f, 0.f, 0.f, 0.f};
                z = MFMA16(aU2[mt][0], *(const bf16x8*)&pb2[0], z, 0, 0, 0);
                z = MFMA16(aU2[mt][1], *(const bf16x8*)&pb2[1], z, 0, 0, 0);
                dD[mt] = z;
            }
            #pragma unroll
            for (int mt = 0; mt < 4; ++mt)
                #pragma unroll
                for (int r = 0; r < 4; ++r)
                    d2[mt][r] = fast_tanh(dC[mt][r] + dD[mt][r]);
            #pragma unroll
            for (int ks = 0; ks < 2; ++ks) {
                pb2[ks].x = cvtpk(d2[2 * ks][0],     d2[2 * ks][1]);
                pb2[ks].y = cvtpk(d2[2 * ks][2],     d2[2 * ks][3]);
                pb2[ks].z = cvtpk(d2[2 * ks + 1][0], d2[2 * ks + 1][1]);
                pb2[ks].w = cvtpk(d2[2 * ks + 1][2], d2[2 * ks + 1][3]);
            }
        }
    }

    // ---- head: out[b] = sigmoid(h2[79] @ Wo + bo), uperm Wo gather ----
    float p = 0.f;
    #pragma unroll
    for (int mt = 0; mt < 4; ++mt) {
        f32x4 w4 = *(const f32x4*)(Wo + 8 * kgrp + 4 * (mt & 1) + 32 * (mt >> 1));
        p += d2[mt][0] * w4[0] + d2[mt][1] * w4[1]
           + d2[mt][2] * w4[2] + d2[mt][3] * w4[3];
    }
    p += __shfl_xor(p, 16, 64);
    p += __shfl_xor(p, 32, 64);
    if (lane < 16) {
        const float z = p + bo[0];
        const float e = __builtin_amdgcn_exp2f(-z * 1.4426950408889634f);
        out[wg * 16 + lane] = __builtin_amdgcn_rcpf(1.0f + e);
    }
}

extern "C" void kernel_launch(void* const* d_in, const int* in_sizes, int n_in,
                              void* d_out, int out_size, void* d_ws, size_t ws_size,
                              hipStream_t stream) {
    const int*   tokens = (const int*)  d_in[0];
    const float* emb    = (const float*)d_in[1];
    const float* W1     = (const float*)d_in[2];
    const float* U1     = (const float*)d_in[3];
    const float* b1     = (const float*)d_in[4];
    const float* W2     = (const float*)d_in[5];
    const float* U2     = (const float*)d_in[6];
    const float* b2     = (const float*)d_in[7];
    const float* Wo     = (const float*)d_in[8];
    const float* bo     = (const float*)d_in[9];
    float* out = (float*)d_out;
    char*  ws  = (char*)d_ws;

    tableproj_kernel<<<(NVWV + 3) / 4, 256, 0, stream>>>(
        emb, b1, W1, (uint2*)(ws + TAB_OFF));
    rnn_kernel<<<NTILE, 64, 0, stream>>>(
        tokens, (const uint2*)(ws + TAB_OFF),
        U1, W2, U2, b2, Wo, bo, out);
}

// Round 26
// 58.478 us; speedup vs baseline: 1.4248x; 1.4248x over previous
//
#include <hip/hip_runtime.h>

#define BATCH 4096
#define SEQ   80
#define EMBED 100
#define UNITS 64
#define NTILE (BATCH / 16)      // 256 batch tiles of 16 rows
#define NVOC  10000
#define NVWV  ((NVOC + 15) / 16)
#define NPAIR2 (SEQ / 2)        // 40 timestep pairs

typedef float f32x4  __attribute__((ext_vector_type(4)));
typedef short bf16x8 __attribute__((ext_vector_type(8)));

#define MFMA16 __builtin_amdgcn_mfma_f32_16x16x32_bf16

// ---- ws layout (bytes) ----
#define TAB_OFF 0u           // bf16 table[10000][64] = 1,280,000 B (L2-resident)
#define XW2_OFF 1280000u     // uint4[256*4*40*64] = 41,943,040 B (pair-packed)

__device__ __forceinline__ unsigned f2bfu(float f) {
    union { float f; unsigned u; } x; x.f = f;
    return (x.u + 0x7fffu + ((x.u >> 16) & 1u)) >> 16;   // RNE
}
__device__ __forceinline__ unsigned cvtpk(float lo, float hi) {
    unsigned r;
    asm("v_cvt_pk_bf16_f32 %0, %1, %2" : "=v"(r) : "v"(lo), "v"(hi));
    return r;
}
__device__ __forceinline__ float bflo(unsigned u) {
    union { unsigned u; float f; } x; x.u = u << 16; return x.f;
}
__device__ __forceinline__ float bfhi(unsigned u) {
    union { unsigned u; float f; } x; x.u = u & 0xffff0000u; return x.f;
}
// branch-free exact-tails tanh: 1 - 2/(e^{2x}+1)
__device__ __forceinline__ float fast_tanh(float x) {
    float e = __builtin_amdgcn_exp2f(x * 2.8853900817779268f);
    float r = __builtin_amdgcn_rcpf(e + 1.0f);
    return __builtin_fmaf(-2.0f, r, 1.0f);
}

// ---------------------------------------------------------------------------
// tableproj: table[v] = b1 + emb[v] @ W1 for all 10000 vocab rows (verified).
// ---------------------------------------------------------------------------
__global__ __launch_bounds__(256) void tableproj_kernel(
    const float* __restrict__ emb,
    const float* __restrict__ b1,
    const float* __restrict__ W1,
    char* __restrict__ table)
{
    const int lane = threadIdx.x & 63;
    const int wid  = threadIdx.x >> 6;
    const int gw   = blockIdx.x * 4 + wid;
    if (gw >= NVWV) return;
    const int m15  = lane & 15;
    const int kgrp = lane >> 4;
    const int v    = gw * 16 + m15;
    const int vc   = v < NVOC ? v : NVOC - 1;

    bf16x8 aW1[4][4];
    #pragma unroll
    for (int mt = 0; mt < 4; ++mt) {
        const int u = 16 * mt + m15;
        #pragma unroll
        for (int ks = 0; ks < 4; ++ks)
            #pragma unroll
            for (int j = 0; j < 8; ++j) {
                const int k = kgrp * 8 + j + 32 * ks;
                aW1[mt][ks][j] = (k < EMBED) ? (short)f2bfu(W1[k * UNITS + u])
                                             : (short)0;
            }
    }

    const float* rp = emb + (size_t)vc * EMBED;
    bf16x8 bf[4];
    #pragma unroll
    for (int ks = 0; ks < 3; ++ks) {
        f32x4 e0 = *(const f32x4*)(rp + kgrp * 8 + 32 * ks);
        f32x4 e1 = *(const f32x4*)(rp + kgrp * 8 + 32 * ks + 4);
        uint4 u;
        u.x = cvtpk(e0.x, e0.y); u.y = cvtpk(e0.z, e0.w);
        u.z = cvtpk(e1.x, e1.y); u.w = cvtpk(e1.z, e1.w);
        bf[ks] = *(bf16x8*)&u;
    }
    {
        uint4 u = {0u, 0u, 0u, 0u};
        if (kgrp == 0) {
            f32x4 e0 = *(const f32x4*)(rp + 96);
            u.x = cvtpk(e0.x, e0.y); u.y = cvtpk(e0.z, e0.w);
        }
        bf[3] = *(bf16x8*)&u;
    }

    f32x4 acc[4];
    #pragma unroll
    for (int mt = 0; mt < 4; ++mt)
        acc[mt] = *(const f32x4*)(b1 + 16 * mt + 4 * kgrp);
    #pragma unroll
    for (int ks = 0; ks < 4; ++ks)
        #pragma unroll
        for (int mt = 0; mt < 4; ++mt)
            acc[mt] = MFMA16(aW1[mt][ks], bf[ks], acc[mt], 0, 0, 0);

    #pragma unroll
    for (int mt = 0; mt < 4; ++mt) {
        uint2 q;
        q.x = cvtpk(acc[mt][0], acc[mt][1]);
        q.y = cvtpk(acc[mt][2], acc[mt][3]);
        *(uint2*)(table + (size_t)v * 128 + mt * 32 + kgrp * 8) = q;
    }
}

// ---------------------------------------------------------------------------
// expand v3: branch-free deep-pipelined. 512 blocks x 4 waves; wave
// (tile, w, half) emits 20 pair-packed lines. Tokens preloaded to registers
// (10 x int4), then ALL 40 gathers issued independently (one L2 latency),
// then 20 coalesced 1KB stores. Output layout identical to R15/R16 (verified).
// ---------------------------------------------------------------------------
__global__ __launch_bounds__(256) void expand_kernel(
    const int*   __restrict__ tokens,
    const uint2* __restrict__ table,     // [10000][16] uint2
    uint4*       __restrict__ xw2)
{
    const int lane = threadIdx.x & 63;
    const int wv   = threadIdx.x >> 6;
    const int tile = blockIdx.x >> 1;
    const int half = blockIdx.x & 1;
    const int m15  = lane & 15;
    const int kgrp = lane >> 4;
    const int pk0  = half * (NPAIR2 / 2);    // 0 or 20

    // preload this lane's 40 tokens (t = 2*pk0 .. 2*pk0+39), 10 x int4
    const int* tokp = tokens + (size_t)(tile * 16 + m15) * SEQ + 2 * pk0;
    int tk[40];
    #pragma unroll
    for (int q = 0; q < 10; ++q) {
        int4 v = *(const int4*)(tokp + 4 * q);
        tk[4 * q + 0] = v.x; tk[4 * q + 1] = v.y;
        tk[4 * q + 2] = v.z; tk[4 * q + 3] = v.w;
    }

    const uint2* tabp = table + wv * 4 + kgrp;
    uint4* outp = xw2 + ((size_t)(tile * 4 + wv)) * NPAIR2 * 64 + lane;

    // all 40 gathers, fully independent
    uint2 gE[20], gO[20];
    #pragma unroll
    for (int i = 0; i < 20; ++i) {
        gE[i] = tabp[(size_t)tk[2 * i] * 16];
        gO[i] = tabp[(size_t)tk[2 * i + 1] * 16];
    }
    // 20 coalesced stores
    #pragma unroll
    for (int i = 0; i < 20; ++i) {
        uint4 o; o.x = gE[i].x; o.y = gE[i].y; o.z = gO[i].x; o.w = gO[i].y;
        outp[(size_t)(pk0 + i) * 64] = o;
    }
}

// ---------------------------------------------------------------------------
// rnn: R16's verified lean stream scan (pair-packed feed, ~900 cyc/phase).
// Weight A-frags from f32 at startup. Byte-identical to R16 (passed).
// ---------------------------------------------------------------------------
__global__ __launch_bounds__(256, 1) void rnn_kernel(
    const uint4*  __restrict__ xw2,
    const float*  __restrict__ U1,
    const float*  __restrict__ W2,
    const float*  __restrict__ U2,
    const float*  __restrict__ b2,
    const float*  __restrict__ Wo,
    const float*  __restrict__ bo,
    float*        __restrict__ out)
{
    __shared__ __align__(16) char h1L[2][2048];   // [buf][16b x 64u bf16, swz]
    __shared__ __align__(16) char h2L[2][2048];
    __shared__ float headp[4][16];

    const int lane = threadIdx.x & 63;
    const int w    = threadIdx.x >> 6;
    const int m15  = lane & 15;
    const int kgrp = lane >> 4;
    const int swz  = (m15 & 7) << 4;
    const int wg   = blockIdx.x;

    {
        uint4 z = {0u, 0u, 0u, 0u};
        if (threadIdx.x < 128) ((uint4*)h2L[0])[threadIdx.x] = z;
    }

    const int urow = 16 * w + m15;
    bf16x8 aU1[2], aW2[2], aU2[2];
    #pragma unroll
    for (int ks = 0; ks < 2; ++ks)
        #pragma unroll
        for (int j = 0; j < 8; ++j) {
            const int k = kgrp * 8 + j + 32 * ks;
            aU1[ks][j] = (short)f2bfu(U1[k * UNITS + urow]);
            aW2[ks][j] = (short)f2bfu(W2[k * UNITS + urow]);
            aU2[ks][j] = (short)f2bfu(U2[k * UNITS + urow]);
        }
    const int ubase = 16 * w + 4 * kgrp;
    const f32x4 b2c = *(const f32x4*)(b2 + ubase);

    // pair-packed stream: pair pk at xwp[pk*64]; holds {xw[2pk], xw[2pk+1]}
    const uint4* xwp = xw2 + ((size_t)(wg * 4 + w)) * NPAIR2 * 64 + lane;
    uint4 r0 = xwp[0];
    uint4 r1 = xwp[64];
    uint4 r2 = xwp[2 * 64];

    // prologue: h1[0] = tanh(xw[0]) -> buf 0   (xw[0] = r0.xy)
    {
        float t0 = fast_tanh(bflo(r0.x)), t1 = fast_tanh(bfhi(r0.x));
        float t2 = fast_tanh(bflo(r0.y)), t3 = fast_tanh(bfhi(r0.y));
        uint2 pk; pk.x = cvtpk(t0, t1); pk.y = cvtpk(t2, t3);
        *(uint2*)(h1L[0] + m15 * 128 + ((32 * w + 8 * kgrp) ^ swz)) = pk;
    }
    asm volatile("s_waitcnt lgkmcnt(0)" ::: "memory");
    __builtin_amdgcn_s_barrier();

    float d2f0 = 0.f, d2f1 = 0.f, d2f2 = 0.f, d2f3 = 0.f;

#define LBAR() do { asm volatile("s_waitcnt lgkmcnt(0)" ::: "memory"); \
                    __builtin_amdgcn_s_barrier(); } while (0)
// One phase; (QX,QY) = packed bf16 xw[T+1]. Math identical to R8 (verified).
#define PHASE(QX, QY, P, Q)                                                      \
  {                                                                              \
    bf16x8 bh1a = *(const bf16x8*)(h1L[P] + m15 * 128 + ((kgrp * 16     ) ^ swz)); \
    bf16x8 bh1b = *(const bf16x8*)(h1L[P] + m15 * 128 + ((kgrp * 16 + 64) ^ swz)); \
    bf16x8 bh2a = *(const bf16x8*)(h2L[P] + m15 * 128 + ((kgrp * 16     ) ^ swz)); \
    bf16x8 bh2b = *(const bf16x8*)(h2L[P] + m15 * 128 + ((kgrp * 16 + 64) ^ swz)); \
    f32x4 d1 = {bflo(QX), bfhi(QX), bflo(QY), bfhi(QY)};                         \
    d1 = MFMA16(aU1[0], bh1a, d1, 0, 0, 0);                                      \
    d1 = MFMA16(aU1[1], bh1b, d1, 0, 0, 0);                                      \
    f32x4 dC = b2c;                                                              \
    dC = MFMA16(aW2[0], bh1a, dC, 0, 0, 0);                                      \
    dC = MFMA16(aW2[1], bh1b, dC, 0, 0, 0);                                      \
    f32x4 dD = {0.f, 0.f, 0.f, 0.f};                                             \
    dD = MFMA16(aU2[0], bh2a, dD, 0, 0, 0);                                      \
    dD = MFMA16(aU2[1], bh2b, dD, 0, 0, 0);                                      \
    float n0 = fast_tanh(d1[0]);                                                 \
    float n1 = fast_tanh(d1[1]);                                                 \
    float n2 = fast_tanh(d1[2]);                                                 \
    float n3 = fast_tanh(d1[3]);                                                 \
    d2f0 = fast_tanh(dC[0] + dD[0]);                                             \
    d2f1 = fast_tanh(dC[1] + dD[1]);                                             \
    d2f2 = fast_tanh(dC[2] + dD[2]);                                             \
    d2f3 = fast_tanh(dC[3] + dD[3]);                                             \
    {                                                                            \
        uint2 pk; pk.x = cvtpk(n0, n1); pk.y = cvtpk(n2, n3);                    \
        *(uint2*)(h1L[Q] + m15 * 128 + ((32 * w + 8 * kgrp) ^ swz)) = pk;        \
    }                                                                            \
    {                                                                            \
        uint2 pk; pk.x = cvtpk(d2f0, d2f1); pk.y = cvtpk(d2f2, d2f3);            \
        *(uint2*)(h2L[Q] + m15 * 128 + ((32 * w + 8 * kgrp) ^ swz)) = pk;        \
    }                                                                            \
    LBAR();                                                                      \
  }

    for (int k = 0; k < NPAIR2; ++k) {
        const int pn = (k + 3 < NPAIR2) ? k + 3 : NPAIR2 - 1;
        uint4 r3 = xwp[(size_t)pn * 64];
        PHASE(r0.z, r0.w, 0, 1)     // phase 2k   uses xw[2k+1]
        PHASE(r1.x, r1.y, 1, 0)     // phase 2k+1 uses xw[2k+2]
        r0 = r1; r1 = r2; r2 = r3;
    }
#undef PHASE
#undef LBAR

    // ---- head: out[b] = sigmoid(h2[79] @ Wo + bo) ----
    const f32x4 woc = *(const f32x4*)(Wo + ubase);
    float p = d2f0 * woc[0] + d2f1 * woc[1] + d2f2 * woc[2] + d2f3 * woc[3];
    p += __shfl_xor(p, 16, 64);
    p += __shfl_xor(p, 32, 64);
    if (lane < 16) headp[w][lane] = p;
    __syncthreads();
    if (threadIdx.x < 16) {
        const float z = headp[0][threadIdx.x] + headp[1][threadIdx.x]
                      + headp[2][threadIdx.x] + headp[3][threadIdx.x] + bo[0];
        const float e = __builtin_amdgcn_exp2f(-z * 1.4426950408889634f);
        out[wg * 16 + threadIdx.x] = __builtin_amdgcn_rcpf(1.0f + e);
    }
}

extern "C" void kernel_launch(void* const* d_in, const int* in_sizes, int n_in,
                              void* d_out, int out_size, void* d_ws, size_t ws_size,
                              hipStream_t stream) {
    const int*   tokens = (const int*)  d_in[0];
    const float* emb    = (const float*)d_in[1];
    const float* W1     = (const float*)d_in[2];
    const float* U1     = (const float*)d_in[3];
    const float* b1     = (const float*)d_in[4];
    const float* W2     = (const float*)d_in[5];
    const float* U2     = (const float*)d_in[6];
    const float* b2     = (const float*)d_in[7];
    const float* Wo     = (const float*)d_in[8];
    const float* bo     = (const float*)d_in[9];
    float* out = (float*)d_out;
    char*  ws  = (char*)d_ws;

    tableproj_kernel<<<(NVWV + 3) / 4, 256, 0, stream>>>(
        emb, b1, W1, ws + TAB_OFF);
    expand_kernel<<<512, 256, 0, stream>>>(
        tokens, (const uint2*)(ws + TAB_OFF), (uint4*)(ws + XW2_OFF));
    rnn_kernel<<<NTILE, 256, 0, stream>>>(
        (const uint4*)(ws + XW2_OFF),
        U1, W2, U2, b2, Wo, bo, out);
}